// Round 1
// baseline (4696.790 us; speedup 1.0000x reference)
//
#include <hip/hip_runtime.h>

constexpr int NN = 100000;   // nodes
constexpr int NE = 1600000;  // edges
constexpr int DD = 64;       // channels
constexpr int NG = 256;      // graphs

// ---------------------------------------------------------------------------
// Scatter: agg[dst] += h[src], 16 threads per edge, float4 per thread.
// unsafeAtomicAdd -> global_atomic_add_f32 (HW atomic, no CAS loop).
// ---------------------------------------------------------------------------
__global__ __launch_bounds__(256) void scatter_k(const float* __restrict__ h,
                                                 const int* __restrict__ ei,
                                                 float* __restrict__ agg) {
    int tid = blockIdx.x * 256 + threadIdx.x;
    int e = tid >> 4;
    if (e >= NE) return;
    int c = tid & 15;
    int src = ei[e];
    int dst = ei[NE + e];
    float4 v = reinterpret_cast<const float4*>(h)[src * 16 + c];
    float* p = agg + dst * 64 + c * 4;
    unsafeAtomicAdd(p + 0, v.x);
    unsafeAtomicAdd(p + 1, v.y);
    unsafeAtomicAdd(p + 2, v.z);
    unsafeAtomicAdd(p + 3, v.w);
}

// ---------------------------------------------------------------------------
// Fused GIN MLP: z = hin + agg; hout = ReLU?( ReLU(z@w1+b1)@w2+b2 )
// One thread per node row. z row lives in LDS (stride 65 -> 2-way bank alias,
// free). acc[64] statically indexed -> stays in VGPRs. Weight reads are
// wave-uniform -> scalar loads.
// ---------------------------------------------------------------------------
__global__ __launch_bounds__(128) void mlp_k(const float* __restrict__ hin,
                                             const float* __restrict__ agg,
                                             float* __restrict__ hout,
                                             const float* __restrict__ w1,
                                             const float* __restrict__ b1,
                                             const float* __restrict__ w2,
                                             const float* __restrict__ b2,
                                             int relu_out) {
    __shared__ float zs[128 * 65];
    int row = blockIdx.x * 128 + threadIdx.x;
    bool active = row < NN;
    float* zr = zs + threadIdx.x * 65;

    if (active) {
        const float4* a4 = reinterpret_cast<const float4*>(hin) + (size_t)row * 16;
        const float4* g4 = reinterpret_cast<const float4*>(agg) + (size_t)row * 16;
#pragma unroll
        for (int i = 0; i < 16; ++i) {
            float4 a = a4[i];
            float4 g = g4[i];
            zr[4 * i + 0] = a.x + g.x;
            zr[4 * i + 1] = a.y + g.y;
            zr[4 * i + 2] = a.z + g.z;
            zr[4 * i + 3] = a.w + g.w;
        }
    }

    float acc[64];
#pragma unroll
    for (int j = 0; j < 64; ++j) acc[j] = b1[j];
    if (active) {
        for (int k = 0; k < 64; ++k) {
            float zk = zr[k];
#pragma unroll
            for (int j = 0; j < 64; ++j) acc[j] = fmaf(zk, w1[k * 64 + j], acc[j]);
        }
    }
    // ReLU, stash h1 back into this thread's LDS slice (z dead now)
#pragma unroll
    for (int j = 0; j < 64; ++j) zr[j] = fmaxf(acc[j], 0.0f);
#pragma unroll
    for (int j = 0; j < 64; ++j) acc[j] = b2[j];
    if (active) {
        for (int k = 0; k < 64; ++k) {
            float zk = zr[k];
#pragma unroll
            for (int j = 0; j < 64; ++j) acc[j] = fmaf(zk, w2[k * 64 + j], acc[j]);
        }
        float4* o4 = reinterpret_cast<float4*>(hout) + (size_t)row * 16;
#pragma unroll
        for (int i = 0; i < 16; ++i) {
            float4 o;
            o.x = acc[4 * i + 0];
            o.y = acc[4 * i + 1];
            o.z = acc[4 * i + 2];
            o.w = acc[4 * i + 3];
            if (relu_out) {
                o.x = fmaxf(o.x, 0.0f);
                o.y = fmaxf(o.y, 0.0f);
                o.z = fmaxf(o.z, 0.0f);
                o.w = fmaxf(o.w, 0.0f);
            }
            o4[i] = o;
        }
    }
}

// ---------------------------------------------------------------------------
// out[g] = fc_b (init), then pool_k accumulates per-node dot(h, fc_w).
// ---------------------------------------------------------------------------
__global__ void init_out_k(float* __restrict__ out, const float* __restrict__ fcb) {
    int g = threadIdx.x;
    if (g < NG) out[g] = fcb[0];
}

__global__ __launch_bounds__(256) void pool_k(const float* __restrict__ h,
                                              const int* __restrict__ batch,
                                              const float* __restrict__ fcw,
                                              float* __restrict__ out) {
    int node = blockIdx.x * 4 + (threadIdx.x >> 6);
    if (node >= NN) return;
    int lane = threadIdx.x & 63;
    float v = h[(size_t)node * 64 + lane] * fcw[lane];
#pragma unroll
    for (int off = 32; off > 0; off >>= 1) v += __shfl_down(v, off, 64);
    if (lane == 0) unsafeAtomicAdd(&out[batch[node]], v);
}

extern "C" void kernel_launch(void* const* d_in, const int* in_sizes, int n_in,
                              void* d_out, int out_size, void* d_ws, size_t ws_size,
                              hipStream_t stream) {
    const float* x = (const float*)d_in[0];
    const int* ei = (const int*)d_in[1];     // [2, E] flat: src = ei[e], dst = ei[E+e]
    const int* batch = (const int*)d_in[2];  // [N], sorted
    const float* w[3][4];
    for (int l = 0; l < 3; ++l)
        for (int i = 0; i < 4; ++i) w[l][i] = (const float*)d_in[3 + l * 4 + i];
    const float* fcw = (const float*)d_in[15];
    const float* fcb = (const float*)d_in[16];
    float* out = (float*)d_out;

    float* agg = (float*)d_ws;                    // N*D floats
    float* hbuf = agg + (size_t)NN * DD;          // N*D floats

    dim3 sblk(256), sgrid((NE * 16 + 255) / 256);
    dim3 mblk(128), mgrid((NN + 127) / 128);
    dim3 pblk(256), pgrid((NN + 3) / 4);

    const float* hin = x;
    for (int l = 0; l < 3; ++l) {
        hipMemsetAsync(agg, 0, (size_t)NN * DD * sizeof(float), stream);
        scatter_k<<<sgrid, sblk, 0, stream>>>(hin, ei, agg);
        mlp_k<<<mgrid, mblk, 0, stream>>>(hin, agg, hbuf, w[l][0], w[l][1], w[l][2],
                                          w[l][3], l < 2 ? 1 : 0);
        hin = hbuf;
    }
    init_out_k<<<1, 256, 0, stream>>>(out, fcb);
    pool_k<<<pgrid, pblk, 0, stream>>>(hbuf, batch, fcw, out);
}

// Round 2
// 1231.893 us; speedup vs baseline: 3.8127x; 3.8127x over previous
//
#include <hip/hip_runtime.h>

constexpr int NN = 100000;   // nodes
constexpr int NE = 1600000;  // edges
constexpr int DD = 64;       // channels
constexpr int NG = 256;      // graphs

// ---------------------------------------------------------------------------
// CSR build: histogram of dst, exclusive scan, fill csr_src sorted by dst.
// ---------------------------------------------------------------------------
__global__ __launch_bounds__(256) void hist_k(const int* __restrict__ ei,
                                              int* __restrict__ deg) {
    int e = blockIdx.x * 256 + threadIdx.x;
    if (e < NE) atomicAdd(&deg[ei[NE + e]], 1);
}

__global__ __launch_bounds__(1024) void scan_k(const int* __restrict__ deg,
                                               int* __restrict__ rowptr,
                                               int* __restrict__ cursor) {
    __shared__ int part[1024];
    int t = threadIdx.x;
    constexpr int CH = (NN + 1023) / 1024;  // 98
    int b = t * CH;
    int e = min(b + CH, NN);
    int s = 0;
    for (int i = b; i < e; ++i) s += deg[i];
    part[t] = s;
    __syncthreads();
    // Hillis-Steele inclusive scan over 1024 partials
    for (int off = 1; off < 1024; off <<= 1) {
        int v = (t >= off) ? part[t - off] : 0;
        __syncthreads();
        part[t] += v;
        __syncthreads();
    }
    int offp = (t == 0) ? 0 : part[t - 1];
    for (int i = b; i < e; ++i) {
        rowptr[i] = offp;
        cursor[i] = offp;
        offp += deg[i];
    }
    if (t == 1023) rowptr[NN] = offp;  // == NE
}

__global__ __launch_bounds__(256) void fill_k(const int* __restrict__ ei,
                                              int* __restrict__ cursor,
                                              int* __restrict__ csr_src) {
    int e = blockIdx.x * 256 + threadIdx.x;
    if (e < NE) {
        int src = ei[e];
        int dst = ei[NE + e];
        int pos = atomicAdd(&cursor[dst], 1);
        csr_src[pos] = src;
    }
}

// ---------------------------------------------------------------------------
// Gather-aggregate: one wave per dst node, lane = channel. Each iteration the
// wave reads one contiguous 256 B source row (L2/L3-resident: h is 25.6 MB).
// Index loads unrolled x4 to overlap gather latency. One coalesced write.
// ---------------------------------------------------------------------------
__global__ __launch_bounds__(256) void gather_k(const float* __restrict__ h,
                                                const int* __restrict__ rowptr,
                                                const int* __restrict__ csr_src,
                                                float* __restrict__ agg) {
    int node = blockIdx.x * 4 + (threadIdx.x >> 6);
    if (node >= NN) return;
    int lane = threadIdx.x & 63;
    int beg = rowptr[node];
    int end = rowptr[node + 1];
    float acc = 0.0f;
    int i = beg;
    for (; i + 4 <= end; i += 4) {
        int s0 = csr_src[i + 0];
        int s1 = csr_src[i + 1];
        int s2 = csr_src[i + 2];
        int s3 = csr_src[i + 3];
        float v0 = h[(size_t)s0 * 64 + lane];
        float v1 = h[(size_t)s1 * 64 + lane];
        float v2 = h[(size_t)s2 * 64 + lane];
        float v3 = h[(size_t)s3 * 64 + lane];
        acc += v0 + v1 + v2 + v3;
    }
    for (; i < end; ++i) acc += h[(size_t)csr_src[i] * 64 + lane];
    agg[(size_t)node * 64 + lane] = acc;
}

// ---------------------------------------------------------------------------
// Fused GIN MLP: z = hin + agg; hout = ReLU?( ReLU(z@w1+b1)@w2+b2 )
// One thread per node row; z row in LDS (stride 65); acc[64] in VGPRs.
// ---------------------------------------------------------------------------
__global__ __launch_bounds__(128) void mlp_k(const float* __restrict__ hin,
                                             const float* __restrict__ agg,
                                             float* __restrict__ hout,
                                             const float* __restrict__ w1,
                                             const float* __restrict__ b1,
                                             const float* __restrict__ w2,
                                             const float* __restrict__ b2,
                                             int relu_out) {
    __shared__ float zs[128 * 65];
    int row = blockIdx.x * 128 + threadIdx.x;
    bool active = row < NN;
    float* zr = zs + threadIdx.x * 65;

    if (active) {
        const float4* a4 = reinterpret_cast<const float4*>(hin) + (size_t)row * 16;
        const float4* g4 = reinterpret_cast<const float4*>(agg) + (size_t)row * 16;
#pragma unroll
        for (int i = 0; i < 16; ++i) {
            float4 a = a4[i];
            float4 g = g4[i];
            zr[4 * i + 0] = a.x + g.x;
            zr[4 * i + 1] = a.y + g.y;
            zr[4 * i + 2] = a.z + g.z;
            zr[4 * i + 3] = a.w + g.w;
        }
    }

    float acc[64];
#pragma unroll
    for (int j = 0; j < 64; ++j) acc[j] = b1[j];
    if (active) {
        for (int k = 0; k < 64; ++k) {
            float zk = zr[k];
#pragma unroll
            for (int j = 0; j < 64; ++j) acc[j] = fmaf(zk, w1[k * 64 + j], acc[j]);
        }
    }
#pragma unroll
    for (int j = 0; j < 64; ++j) zr[j] = fmaxf(acc[j], 0.0f);
#pragma unroll
    for (int j = 0; j < 64; ++j) acc[j] = b2[j];
    if (active) {
        for (int k = 0; k < 64; ++k) {
            float zk = zr[k];
#pragma unroll
            for (int j = 0; j < 64; ++j) acc[j] = fmaf(zk, w2[k * 64 + j], acc[j]);
        }
        float4* o4 = reinterpret_cast<float4*>(hout) + (size_t)row * 16;
#pragma unroll
        for (int i = 0; i < 16; ++i) {
            float4 o;
            o.x = acc[4 * i + 0];
            o.y = acc[4 * i + 1];
            o.z = acc[4 * i + 2];
            o.w = acc[4 * i + 3];
            if (relu_out) {
                o.x = fmaxf(o.x, 0.0f);
                o.y = fmaxf(o.y, 0.0f);
                o.z = fmaxf(o.z, 0.0f);
                o.w = fmaxf(o.w, 0.0f);
            }
            o4[i] = o;
        }
    }
}

// ---------------------------------------------------------------------------
// out[g] = fc_b (init), then pool_k accumulates per-node dot(h, fc_w).
// ---------------------------------------------------------------------------
__global__ void init_out_k(float* __restrict__ out, const float* __restrict__ fcb) {
    int g = threadIdx.x;
    if (g < NG) out[g] = fcb[0];
}

__global__ __launch_bounds__(256) void pool_k(const float* __restrict__ h,
                                              const int* __restrict__ batch,
                                              const float* __restrict__ fcw,
                                              float* __restrict__ out) {
    int node = blockIdx.x * 4 + (threadIdx.x >> 6);
    if (node >= NN) return;
    int lane = threadIdx.x & 63;
    float v = h[(size_t)node * 64 + lane] * fcw[lane];
#pragma unroll
    for (int off = 32; off > 0; off >>= 1) v += __shfl_down(v, off, 64);
    if (lane == 0) unsafeAtomicAdd(&out[batch[node]], v);
}

extern "C" void kernel_launch(void* const* d_in, const int* in_sizes, int n_in,
                              void* d_out, int out_size, void* d_ws, size_t ws_size,
                              hipStream_t stream) {
    const float* x = (const float*)d_in[0];
    const int* ei = (const int*)d_in[1];     // [2, E] flat: src = ei[e], dst = ei[E+e]
    const int* batch = (const int*)d_in[2];  // [N], sorted
    const float* w[3][4];
    for (int l = 0; l < 3; ++l)
        for (int i = 0; i < 4; ++i) w[l][i] = (const float*)d_in[3 + l * 4 + i];
    const float* fcw = (const float*)d_in[15];
    const float* fcb = (const float*)d_in[16];
    float* out = (float*)d_out;

    // workspace layout
    float* agg = (float*)d_ws;                           // N*D floats (25.6 MB)
    float* hbuf = agg + (size_t)NN * DD;                 // N*D floats (25.6 MB)
    int* deg = (int*)(hbuf + (size_t)NN * DD);           // N ints
    int* rowptr = deg + NN;                              // N+1 ints
    int* cursor = rowptr + NN + 1;                       // N ints
    int* csr_src = cursor + NN;                          // E ints (6.4 MB)

    dim3 eblk(256), egrid((NE + 255) / 256);
    dim3 gblk(256), ggrid((NN + 3) / 4);
    dim3 mblk(128), mgrid((NN + 127) / 128);
    dim3 pblk(256), pgrid((NN + 3) / 4);

    // Build CSR (dst-sorted) once; amortized over 3 layers.
    hipMemsetAsync(deg, 0, NN * sizeof(int), stream);
    hist_k<<<egrid, eblk, 0, stream>>>(ei, deg);
    scan_k<<<1, 1024, 0, stream>>>(deg, rowptr, cursor);
    fill_k<<<egrid, eblk, 0, stream>>>(ei, cursor, csr_src);

    const float* hin = x;
    for (int l = 0; l < 3; ++l) {
        gather_k<<<ggrid, gblk, 0, stream>>>(hin, rowptr, csr_src, agg);
        mlp_k<<<mgrid, mblk, 0, stream>>>(hin, agg, hbuf, w[l][0], w[l][1], w[l][2],
                                          w[l][3], l < 2 ? 1 : 0);
        hin = hbuf;
    }
    init_out_k<<<1, 256, 0, stream>>>(out, fcb);
    pool_k<<<pgrid, pblk, 0, stream>>>(hbuf, batch, fcw, out);
}

// Round 3
// 907.398 us; speedup vs baseline: 5.1761x; 1.3576x over previous
//
#include <hip/hip_runtime.h>

constexpr int NN = 100000;   // nodes
constexpr int NE = 1600000;  // edges
constexpr int DD = 64;       // channels
constexpr int NG = 256;      // graphs

// ---------------------------------------------------------------------------
// CSR build: histogram of dst, exclusive scan, fill csr_src sorted by dst.
// ---------------------------------------------------------------------------
__global__ __launch_bounds__(256) void hist_k(const int* __restrict__ ei,
                                              int* __restrict__ deg) {
    int e = blockIdx.x * 256 + threadIdx.x;
    if (e < NE) atomicAdd(&deg[ei[NE + e]], 1);
}

__global__ __launch_bounds__(1024) void scan_k(const int* __restrict__ deg,
                                               int* __restrict__ rowptr,
                                               int* __restrict__ cursor) {
    __shared__ int part[1024];
    int t = threadIdx.x;
    constexpr int CH = (NN + 1023) / 1024;  // 98
    int b = t * CH;
    int e = min(b + CH, NN);
    int s = 0;
    for (int i = b; i < e; ++i) s += deg[i];
    part[t] = s;
    __syncthreads();
    // Hillis-Steele inclusive scan over 1024 partials
    for (int off = 1; off < 1024; off <<= 1) {
        int v = (t >= off) ? part[t - off] : 0;
        __syncthreads();
        part[t] += v;
        __syncthreads();
    }
    int offp = (t == 0) ? 0 : part[t - 1];
    for (int i = b; i < e; ++i) {
        rowptr[i] = offp;
        cursor[i] = offp;
        offp += deg[i];
    }
    if (t == 1023) rowptr[NN] = offp;  // == NE
}

__global__ __launch_bounds__(256) void fill_k(const int* __restrict__ ei,
                                              int* __restrict__ cursor,
                                              int* __restrict__ csr_src) {
    int e = blockIdx.x * 256 + threadIdx.x;
    if (e < NE) {
        int src = ei[e];
        int dst = ei[NE + e];
        int pos = atomicAdd(&cursor[dst], 1);
        csr_src[pos] = src;
    }
}

// ---------------------------------------------------------------------------
// Gather-aggregate: one wave per dst node, lane = channel.
// ---------------------------------------------------------------------------
__global__ __launch_bounds__(256) void gather_k(const float* __restrict__ h,
                                                const int* __restrict__ rowptr,
                                                const int* __restrict__ csr_src,
                                                float* __restrict__ agg) {
    int node = blockIdx.x * 4 + (threadIdx.x >> 6);
    if (node >= NN) return;
    int lane = threadIdx.x & 63;
    int beg = rowptr[node];
    int end = rowptr[node + 1];
    float acc = 0.0f;
    int i = beg;
    for (; i + 4 <= end; i += 4) {
        int s0 = csr_src[i + 0];
        int s1 = csr_src[i + 1];
        int s2 = csr_src[i + 2];
        int s3 = csr_src[i + 3];
        float v0 = h[(size_t)s0 * 64 + lane];
        float v1 = h[(size_t)s1 * 64 + lane];
        float v2 = h[(size_t)s2 * 64 + lane];
        float v3 = h[(size_t)s3 * 64 + lane];
        acc += v0 + v1 + v2 + v3;
    }
    for (; i < end; ++i) acc += h[(size_t)csr_src[i] * 64 + lane];
    agg[(size_t)node * 64 + lane] = acc;
}

// ---------------------------------------------------------------------------
// Fused GIN MLP: z = hin + agg; hout = ReLU?( ReLU(z@w1+b1)@w2+b2 )
// One thread per node row; z row in LDS (stride 65); acc[64] in VGPRs.
// ---------------------------------------------------------------------------
__global__ __launch_bounds__(128) void mlp_k(const float* __restrict__ hin,
                                             const float* __restrict__ agg,
                                             float* __restrict__ hout,
                                             const float* __restrict__ w1,
                                             const float* __restrict__ b1,
                                             const float* __restrict__ w2,
                                             const float* __restrict__ b2,
                                             int relu_out) {
    __shared__ float zs[128 * 65];
    int row = blockIdx.x * 128 + threadIdx.x;
    bool active = row < NN;
    float* zr = zs + threadIdx.x * 65;

    if (active) {
        const float4* a4 = reinterpret_cast<const float4*>(hin) + (size_t)row * 16;
        const float4* g4 = reinterpret_cast<const float4*>(agg) + (size_t)row * 16;
#pragma unroll
        for (int i = 0; i < 16; ++i) {
            float4 a = a4[i];
            float4 g = g4[i];
            zr[4 * i + 0] = a.x + g.x;
            zr[4 * i + 1] = a.y + g.y;
            zr[4 * i + 2] = a.z + g.z;
            zr[4 * i + 3] = a.w + g.w;
        }
    }

    float acc[64];
#pragma unroll
    for (int j = 0; j < 64; ++j) acc[j] = b1[j];
    if (active) {
        for (int k = 0; k < 64; ++k) {
            float zk = zr[k];
#pragma unroll
            for (int j = 0; j < 64; ++j) acc[j] = fmaf(zk, w1[k * 64 + j], acc[j]);
        }
    }
#pragma unroll
    for (int j = 0; j < 64; ++j) zr[j] = fmaxf(acc[j], 0.0f);
#pragma unroll
    for (int j = 0; j < 64; ++j) acc[j] = b2[j];
    if (active) {
        for (int k = 0; k < 64; ++k) {
            float zk = zr[k];
#pragma unroll
            for (int j = 0; j < 64; ++j) acc[j] = fmaf(zk, w2[k * 64 + j], acc[j]);
        }
        float4* o4 = reinterpret_cast<float4*>(hout) + (size_t)row * 16;
#pragma unroll
        for (int i = 0; i < 16; ++i) {
            float4 o;
            o.x = acc[4 * i + 0];
            o.y = acc[4 * i + 1];
            o.z = acc[4 * i + 2];
            o.w = acc[4 * i + 3];
            if (relu_out) {
                o.x = fmaxf(o.x, 0.0f);
                o.y = fmaxf(o.y, 0.0f);
                o.z = fmaxf(o.z, 0.0f);
                o.w = fmaxf(o.w, 0.0f);
            }
            o4[i] = o;
        }
    }
}

// ---------------------------------------------------------------------------
// Pool + FC: one block per graph. batch is SORTED, so binary-search the node
// range [lo, hi) for this graph; 4 waves stride over nodes accumulating
// h[node][lane]*fcw[lane] into per-lane registers; one shuffle+LDS reduce at
// the end; single plain store. Zero atomics.
// ---------------------------------------------------------------------------
__device__ __forceinline__ int lower_bound_i(const int* __restrict__ a, int n, int v) {
    int lo = 0, hi = n;
    while (lo < hi) {
        int mid = (lo + hi) >> 1;
        if (a[mid] < v) lo = mid + 1; else hi = mid;
    }
    return lo;
}

__global__ __launch_bounds__(256) void pool_k(const float* __restrict__ h,
                                              const int* __restrict__ batch,
                                              const float* __restrict__ fcw,
                                              const float* __restrict__ fcb,
                                              float* __restrict__ out) {
    int g = blockIdx.x;
    int lane = threadIdx.x & 63;
    int wv = threadIdx.x >> 6;
    int lo = lower_bound_i(batch, NN, g);
    int hi = lower_bound_i(batch, NN, g + 1);
    float w = fcw[lane];
    float sum = 0.0f;
    for (int node = lo + wv; node < hi; node += 4)
        sum += h[(size_t)node * 64 + lane] * w;
#pragma unroll
    for (int off = 32; off > 0; off >>= 1) sum += __shfl_down(sum, off, 64);
    __shared__ float ws[4];
    if (lane == 0) ws[wv] = sum;
    __syncthreads();
    if (threadIdx.x == 0) out[g] = ws[0] + ws[1] + ws[2] + ws[3] + fcb[0];
}

extern "C" void kernel_launch(void* const* d_in, const int* in_sizes, int n_in,
                              void* d_out, int out_size, void* d_ws, size_t ws_size,
                              hipStream_t stream) {
    const float* x = (const float*)d_in[0];
    const int* ei = (const int*)d_in[1];     // [2, E] flat: src = ei[e], dst = ei[E+e]
    const int* batch = (const int*)d_in[2];  // [N], sorted
    const float* w[3][4];
    for (int l = 0; l < 3; ++l)
        for (int i = 0; i < 4; ++i) w[l][i] = (const float*)d_in[3 + l * 4 + i];
    const float* fcw = (const float*)d_in[15];
    const float* fcb = (const float*)d_in[16];
    float* out = (float*)d_out;

    // workspace layout
    float* agg = (float*)d_ws;                           // N*D floats (25.6 MB)
    float* hbuf = agg + (size_t)NN * DD;                 // N*D floats (25.6 MB)
    int* deg = (int*)(hbuf + (size_t)NN * DD);           // N ints
    int* rowptr = deg + NN;                              // N+1 ints
    int* cursor = rowptr + NN + 1;                       // N ints
    int* csr_src = cursor + NN;                          // E ints (6.4 MB)

    dim3 eblk(256), egrid((NE + 255) / 256);
    dim3 gblk(256), ggrid((NN + 3) / 4);
    dim3 mblk(128), mgrid((NN + 127) / 128);

    // Build CSR (dst-sorted) once; amortized over 3 layers.
    hipMemsetAsync(deg, 0, NN * sizeof(int), stream);
    hist_k<<<egrid, eblk, 0, stream>>>(ei, deg);
    scan_k<<<1, 1024, 0, stream>>>(deg, rowptr, cursor);
    fill_k<<<egrid, eblk, 0, stream>>>(ei, cursor, csr_src);

    const float* hin = x;
    for (int l = 0; l < 3; ++l) {
        gather_k<<<ggrid, gblk, 0, stream>>>(hin, rowptr, csr_src, agg);
        mlp_k<<<mgrid, mblk, 0, stream>>>(hin, agg, hbuf, w[l][0], w[l][1], w[l][2],
                                          w[l][3], l < 2 ? 1 : 0);
        hin = hbuf;
    }
    pool_k<<<NG, 256, 0, stream>>>(hbuf, batch, fcw, fcb, out);
}

// Round 4
// 678.811 us; speedup vs baseline: 6.9191x; 1.3367x over previous
//
#include <hip/hip_runtime.h>

constexpr int NN = 100000;   // nodes
constexpr int NE = 1600000;  // edges
constexpr int DD = 64;       // channels
constexpr int NG = 256;      // graphs
constexpr int NB = (NN + 255) / 256;  // 391 scan blocks

// ---------------------------------------------------------------------------
// CSR build: histogram of dst, hierarchical exclusive scan, fill csr_src.
// ---------------------------------------------------------------------------
__global__ __launch_bounds__(256) void hist_k(const int* __restrict__ ei,
                                              int* __restrict__ deg) {
    int e = blockIdx.x * 256 + threadIdx.x;
    if (e < NE) atomicAdd(&deg[ei[NE + e]], 1);
}

// Phase A: per-block (256-wide) sums of deg.
__global__ __launch_bounds__(256) void reduce_k(const int* __restrict__ deg,
                                                int* __restrict__ bsum) {
    int i = blockIdx.x * 256 + threadIdx.x;
    int v = (i < NN) ? deg[i] : 0;
#pragma unroll
    for (int off = 32; off > 0; off >>= 1) v += __shfl_down(v, off, 64);
    __shared__ int ws[4];
    if ((threadIdx.x & 63) == 0) ws[threadIdx.x >> 6] = v;
    __syncthreads();
    if (threadIdx.x == 0) bsum[blockIdx.x] = ws[0] + ws[1] + ws[2] + ws[3];
}

// Phase B: exclusive scan of the NB block sums (single tiny block).
__global__ __launch_bounds__(512) void scanb_k(const int* __restrict__ bsum,
                                               int* __restrict__ bpre) {
    __shared__ int sh[512];
    int t = threadIdx.x;
    int v = (t < NB) ? bsum[t] : 0;
    sh[t] = v;
    __syncthreads();
    for (int off = 1; off < 512; off <<= 1) {
        int u = (t >= off) ? sh[t - off] : 0;
        __syncthreads();
        sh[t] += u;
        __syncthreads();
    }
    if (t < NB) bpre[t] = sh[t] - v;
}

// Phase C: block-local scan + block prefix -> rowptr, cursor.
__global__ __launch_bounds__(256) void scan_scatter_k(const int* __restrict__ deg,
                                                      const int* __restrict__ bpre,
                                                      int* __restrict__ rowptr,
                                                      int* __restrict__ cursor) {
    __shared__ int sh[256];
    int t = threadIdx.x;
    int i = blockIdx.x * 256 + t;
    int v = (i < NN) ? deg[i] : 0;
    sh[t] = v;
    __syncthreads();
    for (int off = 1; off < 256; off <<= 1) {
        int u = (t >= off) ? sh[t - off] : 0;
        __syncthreads();
        sh[t] += u;
        __syncthreads();
    }
    int excl = sh[t] - v + bpre[blockIdx.x];
    if (i < NN) {
        rowptr[i] = excl;
        cursor[i] = excl;
        if (i == NN - 1) rowptr[NN] = excl + v;
    }
}

__global__ __launch_bounds__(256) void fill_k(const int* __restrict__ ei,
                                              int* __restrict__ cursor,
                                              int* __restrict__ csr_src) {
    int e = blockIdx.x * 256 + threadIdx.x;
    if (e < NE) {
        int src = ei[e];
        int dst = ei[NE + e];
        int pos = atomicAdd(&cursor[dst], 1);
        csr_src[pos] = src;
    }
}

// ---------------------------------------------------------------------------
// Gather-aggregate: one wave per dst node. 16 lanes x float4 cover one 256 B
// source row; the wave's 4 groups of 16 lanes take every 4th edge -> each
// load instruction fetches 4 rows (1 KB). Group partials combined with two
// shuffle rounds; lanes 0-15 store the row as float4.
// ---------------------------------------------------------------------------
__global__ __launch_bounds__(256) void gather_k(const float* __restrict__ h,
                                                const int* __restrict__ rowptr,
                                                const int* __restrict__ csr_src,
                                                float* __restrict__ agg) {
    int node = blockIdx.x * 4 + (threadIdx.x >> 6);
    if (node >= NN) return;
    int lane = threadIdx.x & 63;
    int c = lane & 15;    // float4 slot within the row
    int grp = lane >> 4;  // edge group 0..3
    int beg = rowptr[node];
    int end = rowptr[node + 1];
    const float4* h4 = reinterpret_cast<const float4*>(h);
    float4 acc = make_float4(0.f, 0.f, 0.f, 0.f);
    for (int i = beg + grp; i < end; i += 4) {
        int s = csr_src[i];
        float4 v = h4[(size_t)s * 16 + c];
        acc.x += v.x;
        acc.y += v.y;
        acc.z += v.z;
        acc.w += v.w;
    }
#pragma unroll
    for (int off = 32; off >= 16; off >>= 1) {
        acc.x += __shfl_down(acc.x, off, 64);
        acc.y += __shfl_down(acc.y, off, 64);
        acc.z += __shfl_down(acc.z, off, 64);
        acc.w += __shfl_down(acc.w, off, 64);
    }
    if (lane < 16) reinterpret_cast<float4*>(agg)[(size_t)node * 16 + c] = acc;
}

// ---------------------------------------------------------------------------
// Fused GIN MLP: z = hin + agg; hout = ReLU?( ReLU(z@w1+b1)@w2+b2 )
// One thread per node row; z row in LDS (stride 65); acc[64] in VGPRs.
// ---------------------------------------------------------------------------
__global__ __launch_bounds__(128) void mlp_k(const float* __restrict__ hin,
                                             const float* __restrict__ agg,
                                             float* __restrict__ hout,
                                             const float* __restrict__ w1,
                                             const float* __restrict__ b1,
                                             const float* __restrict__ w2,
                                             const float* __restrict__ b2,
                                             int relu_out) {
    __shared__ float zs[128 * 65];
    int row = blockIdx.x * 128 + threadIdx.x;
    bool active = row < NN;
    float* zr = zs + threadIdx.x * 65;

    if (active) {
        const float4* a4 = reinterpret_cast<const float4*>(hin) + (size_t)row * 16;
        const float4* g4 = reinterpret_cast<const float4*>(agg) + (size_t)row * 16;
#pragma unroll
        for (int i = 0; i < 16; ++i) {
            float4 a = a4[i];
            float4 g = g4[i];
            zr[4 * i + 0] = a.x + g.x;
            zr[4 * i + 1] = a.y + g.y;
            zr[4 * i + 2] = a.z + g.z;
            zr[4 * i + 3] = a.w + g.w;
        }
    }

    float acc[64];
#pragma unroll
    for (int j = 0; j < 64; ++j) acc[j] = b1[j];
    if (active) {
        for (int k = 0; k < 64; ++k) {
            float zk = zr[k];
#pragma unroll
            for (int j = 0; j < 64; ++j) acc[j] = fmaf(zk, w1[k * 64 + j], acc[j]);
        }
    }
#pragma unroll
    for (int j = 0; j < 64; ++j) zr[j] = fmaxf(acc[j], 0.0f);
#pragma unroll
    for (int j = 0; j < 64; ++j) acc[j] = b2[j];
    if (active) {
        for (int k = 0; k < 64; ++k) {
            float zk = zr[k];
#pragma unroll
            for (int j = 0; j < 64; ++j) acc[j] = fmaf(zk, w2[k * 64 + j], acc[j]);
        }
        float4* o4 = reinterpret_cast<float4*>(hout) + (size_t)row * 16;
#pragma unroll
        for (int i = 0; i < 16; ++i) {
            float4 o;
            o.x = acc[4 * i + 0];
            o.y = acc[4 * i + 1];
            o.z = acc[4 * i + 2];
            o.w = acc[4 * i + 3];
            if (relu_out) {
                o.x = fmaxf(o.x, 0.0f);
                o.y = fmaxf(o.y, 0.0f);
                o.z = fmaxf(o.z, 0.0f);
                o.w = fmaxf(o.w, 0.0f);
            }
            o4[i] = o;
        }
    }
}

// ---------------------------------------------------------------------------
// Pool + FC: one block per graph; batch sorted -> binary-search node range.
// ---------------------------------------------------------------------------
__device__ __forceinline__ int lower_bound_i(const int* __restrict__ a, int n, int v) {
    int lo = 0, hi = n;
    while (lo < hi) {
        int mid = (lo + hi) >> 1;
        if (a[mid] < v) lo = mid + 1; else hi = mid;
    }
    return lo;
}

__global__ __launch_bounds__(256) void pool_k(const float* __restrict__ h,
                                              const int* __restrict__ batch,
                                              const float* __restrict__ fcw,
                                              const float* __restrict__ fcb,
                                              float* __restrict__ out) {
    int g = blockIdx.x;
    int lane = threadIdx.x & 63;
    int wv = threadIdx.x >> 6;
    int lo = lower_bound_i(batch, NN, g);
    int hi = lower_bound_i(batch, NN, g + 1);
    float w = fcw[lane];
    float sum = 0.0f;
    for (int node = lo + wv; node < hi; node += 4)
        sum += h[(size_t)node * 64 + lane] * w;
#pragma unroll
    for (int off = 32; off > 0; off >>= 1) sum += __shfl_down(sum, off, 64);
    __shared__ float ws[4];
    if (lane == 0) ws[wv] = sum;
    __syncthreads();
    if (threadIdx.x == 0) out[g] = ws[0] + ws[1] + ws[2] + ws[3] + fcb[0];
}

extern "C" void kernel_launch(void* const* d_in, const int* in_sizes, int n_in,
                              void* d_out, int out_size, void* d_ws, size_t ws_size,
                              hipStream_t stream) {
    const float* x = (const float*)d_in[0];
    const int* ei = (const int*)d_in[1];     // [2, E] flat: src = ei[e], dst = ei[E+e]
    const int* batch = (const int*)d_in[2];  // [N], sorted
    const float* w[3][4];
    for (int l = 0; l < 3; ++l)
        for (int i = 0; i < 4; ++i) w[l][i] = (const float*)d_in[3 + l * 4 + i];
    const float* fcw = (const float*)d_in[15];
    const float* fcb = (const float*)d_in[16];
    float* out = (float*)d_out;

    // workspace layout
    float* agg = (float*)d_ws;                           // N*D floats (25.6 MB)
    float* hbuf = agg + (size_t)NN * DD;                 // N*D floats (25.6 MB)
    int* deg = (int*)(hbuf + (size_t)NN * DD);           // N ints
    int* rowptr = deg + NN;                              // N+1 ints
    int* cursor = rowptr + NN + 1;                       // N ints
    int* csr_src = cursor + NN;                          // E ints (6.4 MB)
    int* bsum = csr_src + NE;                            // NB ints
    int* bpre = bsum + NB;                               // NB ints

    dim3 eblk(256), egrid((NE + 255) / 256);
    dim3 gblk(256), ggrid((NN + 3) / 4);
    dim3 mblk(128), mgrid((NN + 127) / 128);

    // Build CSR (dst-sorted) once; amortized over 3 layers.
    hipMemsetAsync(deg, 0, NN * sizeof(int), stream);
    hist_k<<<egrid, eblk, 0, stream>>>(ei, deg);
    reduce_k<<<NB, 256, 0, stream>>>(deg, bsum);
    scanb_k<<<1, 512, 0, stream>>>(bsum, bpre);
    scan_scatter_k<<<NB, 256, 0, stream>>>(deg, bpre, rowptr, cursor);
    fill_k<<<egrid, eblk, 0, stream>>>(ei, cursor, csr_src);

    const float* hin = x;
    for (int l = 0; l < 3; ++l) {
        gather_k<<<ggrid, gblk, 0, stream>>>(hin, rowptr, csr_src, agg);
        mlp_k<<<mgrid, mblk, 0, stream>>>(hin, agg, hbuf, w[l][0], w[l][1], w[l][2],
                                          w[l][3], l < 2 ? 1 : 0);
        hin = hbuf;
    }
    pool_k<<<NG, 256, 0, stream>>>(hbuf, batch, fcw, fcb, out);
}

// Round 5
// 547.386 us; speedup vs baseline: 8.5804x; 1.2401x over previous
//
#include <hip/hip_runtime.h>

constexpr int NN = 100000;   // nodes
constexpr int NE = 1600000;  // edges
constexpr int DD = 64;       // channels
constexpr int NG = 256;      // graphs

constexpr int BKT_SHIFT = 8;                   // 256 nodes per bucket
constexpr int NBKT = (NN + 255) >> BKT_SHIFT;  // 391 buckets
constexpr int EPB = 4096;                      // edges per block (build kernels)
constexpr int NEB = (NE + EPB - 1) / EPB;      // 391 blocks

// ---------------------------------------------------------------------------
// CSR build, two-level counting sort.
// Level 1: bucket (dst>>8) histogram -> scan -> pair scatter into exclusive
//          per-block windows (L2-friendly bursts).
// Level 2: one block per bucket: LDS node histogram + scan -> rowptr, then
//          cursor-fill csr_src within the bucket's own 32 KB region.
// ---------------------------------------------------------------------------
__global__ __launch_bounds__(256) void bhist_k(const int* __restrict__ ei,
                                               int* __restrict__ gbkt) {
    __shared__ int lc[NBKT];
    for (int i = threadIdx.x; i < NBKT; i += 256) lc[i] = 0;
    __syncthreads();
    int base = blockIdx.x * EPB;
    int end = min(base + EPB, NE);
    for (int e = base + threadIdx.x; e < end; e += 256)
        atomicAdd(&lc[ei[NE + e] >> BKT_SHIFT], 1);
    __syncthreads();
    for (int i = threadIdx.x; i < NBKT; i += 256)
        if (lc[i]) atomicAdd(&gbkt[i], lc[i]);
}

__global__ __launch_bounds__(512) void bscan_k(const int* __restrict__ gbkt,
                                               int* __restrict__ bbase,
                                               int* __restrict__ bcur) {
    __shared__ int sh[512];
    int t = threadIdx.x;
    int v = (t < NBKT) ? gbkt[t] : 0;
    sh[t] = v;
    __syncthreads();
    for (int off = 1; off < 512; off <<= 1) {
        int u = (t >= off) ? sh[t - off] : 0;
        __syncthreads();
        sh[t] += u;
        __syncthreads();
    }
    if (t < NBKT) {
        bbase[t] = sh[t] - v;
        bcur[t] = sh[t] - v;
    }
}

__global__ __launch_bounds__(256) void pscat_k(const int* __restrict__ ei,
                                               int* __restrict__ bcur,
                                               int2* __restrict__ pairs) {
    __shared__ int lc[NBKT];
    __shared__ int gb[NBKT];
    for (int i = threadIdx.x; i < NBKT; i += 256) lc[i] = 0;
    __syncthreads();
    int base = blockIdx.x * EPB;
    int end = min(base + EPB, NE);
    for (int e = base + threadIdx.x; e < end; e += 256)
        atomicAdd(&lc[ei[NE + e] >> BKT_SHIFT], 1);
    __syncthreads();
    for (int i = threadIdx.x; i < NBKT; i += 256) {
        int c = lc[i];
        gb[i] = c ? atomicAdd(&bcur[i], c) : 0;  // reserve exclusive window
    }
    __syncthreads();
    for (int i = threadIdx.x; i < NBKT; i += 256) lc[i] = 0;  // reuse as cursor
    __syncthreads();
    for (int e = base + threadIdx.x; e < end; e += 256) {
        int src = ei[e];
        int dst = ei[NE + e];
        int b = dst >> BKT_SHIFT;
        int pos = gb[b] + atomicAdd(&lc[b], 1);
        pairs[pos] = make_int2(src, dst);
    }
}

__global__ __launch_bounds__(256) void bfill_k(const int2* __restrict__ pairs,
                                               const int* __restrict__ bbase,
                                               const int* __restrict__ gbkt,
                                               int* __restrict__ rowptr,
                                               int* __restrict__ csr_src) {
    __shared__ int ldeg[256];
    __shared__ int sh[256];
    __shared__ int lcur[256];
    int b = blockIdx.x;
    int t = threadIdx.x;
    int nbase = b << BKT_SHIFT;
    int pbeg = bbase[b];
    int pcnt = gbkt[b];
    ldeg[t] = 0;
    __syncthreads();
    for (int i = t; i < pcnt; i += 256)
        atomicAdd(&ldeg[pairs[pbeg + i].y & 255], 1);
    __syncthreads();
    int v = ldeg[t];
    sh[t] = v;
    __syncthreads();
    for (int off = 1; off < 256; off <<= 1) {
        int u = (t >= off) ? sh[t - off] : 0;
        __syncthreads();
        sh[t] += u;
        __syncthreads();
    }
    int lexcl = sh[t] - v;
    int node = nbase + t;
    if (node < NN) {
        rowptr[node] = pbeg + lexcl;
        if (node == NN - 1) rowptr[NN] = pbeg + lexcl + v;
    }
    lcur[t] = lexcl;
    __syncthreads();
    for (int i = t; i < pcnt; i += 256) {
        int2 p = pairs[pbeg + i];
        int pos = atomicAdd(&lcur[p.y & 255], 1);
        csr_src[pbeg + pos] = p.x;
    }
}

// ---------------------------------------------------------------------------
// Gather-aggregate: one wave per dst node. 16 lanes x float4 per row, 4 edge
// groups per wave; shuffle-combine; lanes 0-15 store the row.
// ---------------------------------------------------------------------------
__global__ __launch_bounds__(256) void gather_k(const float* __restrict__ h,
                                                const int* __restrict__ rowptr,
                                                const int* __restrict__ csr_src,
                                                float* __restrict__ agg) {
    int node = blockIdx.x * 4 + (threadIdx.x >> 6);
    if (node >= NN) return;
    int lane = threadIdx.x & 63;
    int c = lane & 15;    // float4 slot within the row
    int grp = lane >> 4;  // edge group 0..3
    int beg = rowptr[node];
    int end = rowptr[node + 1];
    const float4* h4 = reinterpret_cast<const float4*>(h);
    float4 acc = make_float4(0.f, 0.f, 0.f, 0.f);
    for (int i = beg + grp; i < end; i += 4) {
        int s = csr_src[i];
        float4 v = h4[(size_t)s * 16 + c];
        acc.x += v.x;
        acc.y += v.y;
        acc.z += v.z;
        acc.w += v.w;
    }
#pragma unroll
    for (int off = 32; off >= 16; off >>= 1) {
        acc.x += __shfl_down(acc.x, off, 64);
        acc.y += __shfl_down(acc.y, off, 64);
        acc.z += __shfl_down(acc.z, off, 64);
        acc.w += __shfl_down(acc.w, off, 64);
    }
    if (lane < 16) reinterpret_cast<float4*>(agg)[(size_t)node * 16 + c] = acc;
}

// ---------------------------------------------------------------------------
// Fused GIN MLP: z = hin + agg; hout = ReLU?( ReLU(z@w1+b1)@w2+b2 )
// ---------------------------------------------------------------------------
__global__ __launch_bounds__(128) void mlp_k(const float* __restrict__ hin,
                                             const float* __restrict__ agg,
                                             float* __restrict__ hout,
                                             const float* __restrict__ w1,
                                             const float* __restrict__ b1,
                                             const float* __restrict__ w2,
                                             const float* __restrict__ b2,
                                             int relu_out) {
    __shared__ float zs[128 * 65];
    int row = blockIdx.x * 128 + threadIdx.x;
    bool active = row < NN;
    float* zr = zs + threadIdx.x * 65;

    if (active) {
        const float4* a4 = reinterpret_cast<const float4*>(hin) + (size_t)row * 16;
        const float4* g4 = reinterpret_cast<const float4*>(agg) + (size_t)row * 16;
#pragma unroll
        for (int i = 0; i < 16; ++i) {
            float4 a = a4[i];
            float4 g = g4[i];
            zr[4 * i + 0] = a.x + g.x;
            zr[4 * i + 1] = a.y + g.y;
            zr[4 * i + 2] = a.z + g.z;
            zr[4 * i + 3] = a.w + g.w;
        }
    }

    float acc[64];
#pragma unroll
    for (int j = 0; j < 64; ++j) acc[j] = b1[j];
    if (active) {
        for (int k = 0; k < 64; ++k) {
            float zk = zr[k];
#pragma unroll
            for (int j = 0; j < 64; ++j) acc[j] = fmaf(zk, w1[k * 64 + j], acc[j]);
        }
    }
#pragma unroll
    for (int j = 0; j < 64; ++j) zr[j] = fmaxf(acc[j], 0.0f);
#pragma unroll
    for (int j = 0; j < 64; ++j) acc[j] = b2[j];
    if (active) {
        for (int k = 0; k < 64; ++k) {
            float zk = zr[k];
#pragma unroll
            for (int j = 0; j < 64; ++j) acc[j] = fmaf(zk, w2[k * 64 + j], acc[j]);
        }
        float4* o4 = reinterpret_cast<float4*>(hout) + (size_t)row * 16;
#pragma unroll
        for (int i = 0; i < 16; ++i) {
            float4 o;
            o.x = acc[4 * i + 0];
            o.y = acc[4 * i + 1];
            o.z = acc[4 * i + 2];
            o.w = acc[4 * i + 3];
            if (relu_out) {
                o.x = fmaxf(o.x, 0.0f);
                o.y = fmaxf(o.y, 0.0f);
                o.z = fmaxf(o.z, 0.0f);
                o.w = fmaxf(o.w, 0.0f);
            }
            o4[i] = o;
        }
    }
}

// ---------------------------------------------------------------------------
// Pool + FC: one block per graph; batch sorted -> binary-search node range.
// ---------------------------------------------------------------------------
__device__ __forceinline__ int lower_bound_i(const int* __restrict__ a, int n, int v) {
    int lo = 0, hi = n;
    while (lo < hi) {
        int mid = (lo + hi) >> 1;
        if (a[mid] < v) lo = mid + 1; else hi = mid;
    }
    return lo;
}

__global__ __launch_bounds__(256) void pool_k(const float* __restrict__ h,
                                              const int* __restrict__ batch,
                                              const float* __restrict__ fcw,
                                              const float* __restrict__ fcb,
                                              float* __restrict__ out) {
    int g = blockIdx.x;
    int lane = threadIdx.x & 63;
    int wv = threadIdx.x >> 6;
    int lo = lower_bound_i(batch, NN, g);
    int hi = lower_bound_i(batch, NN, g + 1);
    float w = fcw[lane];
    float sum = 0.0f;
    for (int node = lo + wv; node < hi; node += 4)
        sum += h[(size_t)node * 64 + lane] * w;
#pragma unroll
    for (int off = 32; off > 0; off >>= 1) sum += __shfl_down(sum, off, 64);
    __shared__ float ws[4];
    if (lane == 0) ws[wv] = sum;
    __syncthreads();
    if (threadIdx.x == 0) out[g] = ws[0] + ws[1] + ws[2] + ws[3] + fcb[0];
}

extern "C" void kernel_launch(void* const* d_in, const int* in_sizes, int n_in,
                              void* d_out, int out_size, void* d_ws, size_t ws_size,
                              hipStream_t stream) {
    const float* x = (const float*)d_in[0];
    const int* ei = (const int*)d_in[1];     // [2, E] flat: src = ei[e], dst = ei[E+e]
    const int* batch = (const int*)d_in[2];  // [N], sorted
    const float* w[3][4];
    for (int l = 0; l < 3; ++l)
        for (int i = 0; i < 4; ++i) w[l][i] = (const float*)d_in[3 + l * 4 + i];
    const float* fcw = (const float*)d_in[15];
    const float* fcb = (const float*)d_in[16];
    float* out = (float*)d_out;

    // workspace layout
    float* agg = (float*)d_ws;                           // N*D floats (25.6 MB)
    float* hbuf = agg + (size_t)NN * DD;                 // N*D floats (25.6 MB)
    int* rowptr = (int*)(hbuf + (size_t)NN * DD);        // N+1 ints
    int* csr_src = rowptr + NN + 1;                      // E ints (6.4 MB)
    int* gbkt = csr_src + NE;                            // NBKT ints
    int* bbase = gbkt + NBKT;                            // NBKT ints
    int* bcur = bbase + NBKT;                            // NBKT ints
    // pairs alias agg: consumed by bfill_k before the first gather writes agg
    int2* pairs = (int2*)agg;                            // E int2 (12.8 MB)

    dim3 gblk(256), ggrid((NN + 3) / 4);
    dim3 mblk(128), mgrid((NN + 127) / 128);

    // Build CSR (dst-bucketed counting sort); amortized over 3 layers.
    hipMemsetAsync(gbkt, 0, NBKT * sizeof(int), stream);
    bhist_k<<<NEB, 256, 0, stream>>>(ei, gbkt);
    bscan_k<<<1, 512, 0, stream>>>(gbkt, bbase, bcur);
    pscat_k<<<NEB, 256, 0, stream>>>(ei, bcur, pairs);
    bfill_k<<<NBKT, 256, 0, stream>>>(pairs, bbase, gbkt, rowptr, csr_src);

    const float* hin = x;
    for (int l = 0; l < 3; ++l) {
        gather_k<<<ggrid, gblk, 0, stream>>>(hin, rowptr, csr_src, agg);
        mlp_k<<<mgrid, mblk, 0, stream>>>(hin, agg, hbuf, w[l][0], w[l][1], w[l][2],
                                          w[l][3], l < 2 ? 1 : 0);
        hin = hbuf;
    }
    pool_k<<<NG, 256, 0, stream>>>(hbuf, batch, fcw, fcb, out);
}

// Round 6
// 469.575 us; speedup vs baseline: 10.0022x; 1.1657x over previous
//
#include <hip/hip_runtime.h>

constexpr int NN = 100000;   // nodes
constexpr int NE = 1600000;  // edges
constexpr int DD = 64;       // channels
constexpr int NG = 256;      // graphs

constexpr int BKT_SHIFT = 8;                   // 256 nodes per bucket
constexpr int NBKT = (NN + 255) >> BKT_SHIFT;  // 391 buckets
constexpr int EPB = 4096;                      // edges per block (build kernels)
constexpr int NEB = (NE + EPB - 1) / EPB;      // 391 blocks

// ---------------------------------------------------------------------------
// CSR build, two-level counting sort (unchanged from round 4).
// ---------------------------------------------------------------------------
__global__ __launch_bounds__(256) void bhist_k(const int* __restrict__ ei,
                                               int* __restrict__ gbkt) {
    __shared__ int lc[NBKT];
    for (int i = threadIdx.x; i < NBKT; i += 256) lc[i] = 0;
    __syncthreads();
    int base = blockIdx.x * EPB;
    int end = min(base + EPB, NE);
    for (int e = base + threadIdx.x; e < end; e += 256)
        atomicAdd(&lc[ei[NE + e] >> BKT_SHIFT], 1);
    __syncthreads();
    for (int i = threadIdx.x; i < NBKT; i += 256)
        if (lc[i]) atomicAdd(&gbkt[i], lc[i]);
}

__global__ __launch_bounds__(512) void bscan_k(const int* __restrict__ gbkt,
                                               int* __restrict__ bbase,
                                               int* __restrict__ bcur) {
    __shared__ int sh[512];
    int t = threadIdx.x;
    int v = (t < NBKT) ? gbkt[t] : 0;
    sh[t] = v;
    __syncthreads();
    for (int off = 1; off < 512; off <<= 1) {
        int u = (t >= off) ? sh[t - off] : 0;
        __syncthreads();
        sh[t] += u;
        __syncthreads();
    }
    if (t < NBKT) {
        bbase[t] = sh[t] - v;
        bcur[t] = sh[t] - v;
    }
}

__global__ __launch_bounds__(256) void pscat_k(const int* __restrict__ ei,
                                               int* __restrict__ bcur,
                                               int2* __restrict__ pairs) {
    __shared__ int lc[NBKT];
    __shared__ int gb[NBKT];
    for (int i = threadIdx.x; i < NBKT; i += 256) lc[i] = 0;
    __syncthreads();
    int base = blockIdx.x * EPB;
    int end = min(base + EPB, NE);
    for (int e = base + threadIdx.x; e < end; e += 256)
        atomicAdd(&lc[ei[NE + e] >> BKT_SHIFT], 1);
    __syncthreads();
    for (int i = threadIdx.x; i < NBKT; i += 256) {
        int c = lc[i];
        gb[i] = c ? atomicAdd(&bcur[i], c) : 0;  // reserve exclusive window
    }
    __syncthreads();
    for (int i = threadIdx.x; i < NBKT; i += 256) lc[i] = 0;  // reuse as cursor
    __syncthreads();
    for (int e = base + threadIdx.x; e < end; e += 256) {
        int src = ei[e];
        int dst = ei[NE + e];
        int b = dst >> BKT_SHIFT;
        int pos = gb[b] + atomicAdd(&lc[b], 1);
        pairs[pos] = make_int2(src, dst);
    }
}

__global__ __launch_bounds__(256) void bfill_k(const int2* __restrict__ pairs,
                                               const int* __restrict__ bbase,
                                               const int* __restrict__ gbkt,
                                               int* __restrict__ rowptr,
                                               int* __restrict__ csr_src) {
    __shared__ int ldeg[256];
    __shared__ int sh[256];
    __shared__ int lcur[256];
    int b = blockIdx.x;
    int t = threadIdx.x;
    int nbase = b << BKT_SHIFT;
    int pbeg = bbase[b];
    int pcnt = gbkt[b];
    ldeg[t] = 0;
    __syncthreads();
    for (int i = t; i < pcnt; i += 256)
        atomicAdd(&ldeg[pairs[pbeg + i].y & 255], 1);
    __syncthreads();
    int v = ldeg[t];
    sh[t] = v;
    __syncthreads();
    for (int off = 1; off < 256; off <<= 1) {
        int u = (t >= off) ? sh[t - off] : 0;
        __syncthreads();
        sh[t] += u;
        __syncthreads();
    }
    int lexcl = sh[t] - v;
    int node = nbase + t;
    if (node < NN) {
        rowptr[node] = pbeg + lexcl;
        if (node == NN - 1) rowptr[NN] = pbeg + lexcl + v;
    }
    lcur[t] = lexcl;
    __syncthreads();
    for (int i = t; i < pcnt; i += 256) {
        int2 p = pairs[pbeg + i];
        int pos = atomicAdd(&lcur[p.y & 255], 1);
        csr_src[pbeg + pos] = p.x;
    }
}

// ---------------------------------------------------------------------------
// Gather-aggregate: one wave per dst node (unchanged).
// ---------------------------------------------------------------------------
__global__ __launch_bounds__(256) void gather_k(const float* __restrict__ h,
                                                const int* __restrict__ rowptr,
                                                const int* __restrict__ csr_src,
                                                float* __restrict__ agg) {
    int node = blockIdx.x * 4 + (threadIdx.x >> 6);
    if (node >= NN) return;
    int lane = threadIdx.x & 63;
    int c = lane & 15;    // float4 slot within the row
    int grp = lane >> 4;  // edge group 0..3
    int beg = rowptr[node];
    int end = rowptr[node + 1];
    const float4* h4 = reinterpret_cast<const float4*>(h);
    float4 acc = make_float4(0.f, 0.f, 0.f, 0.f);
    for (int i = beg + grp; i < end; i += 4) {
        int s = csr_src[i];
        float4 v = h4[(size_t)s * 16 + c];
        acc.x += v.x;
        acc.y += v.y;
        acc.z += v.z;
        acc.w += v.w;
    }
#pragma unroll
    for (int off = 32; off >= 16; off >>= 1) {
        acc.x += __shfl_down(acc.x, off, 64);
        acc.y += __shfl_down(acc.y, off, 64);
        acc.z += __shfl_down(acc.z, off, 64);
        acc.w += __shfl_down(acc.w, off, 64);
    }
    if (lane < 16) reinterpret_cast<float4*>(agg)[(size_t)node * 16 + c] = acc;
}

// ---------------------------------------------------------------------------
// Fused GIN MLP as register-blocked LDS-tiled GEMM.
// Block = 256 threads, 64-row tile, whole 64-col width.
// zT[k][r] (stride 68, 17.4 KB) + weight matrix in LDS (16 KB; w1 then w2
// overwritten between barriers) -> 33.8 KB/block -> 4 blocks/CU (16 waves).
// Thread (tr=tid&15, tc=tid>>4) owns a 4x4 fragment: rows 4tr.., cols 4tc..
// Per k: 2x ds_read_b128 + 16 FMA.
// ---------------------------------------------------------------------------
constexpr int ZS = 68;  // zT leading-dim pad: 68*4 B = 272 B (16 B-aligned rows)

__global__ __launch_bounds__(256) void mlp_k(const float* __restrict__ hin,
                                             const float* __restrict__ agg,
                                             float* __restrict__ hout,
                                             const float* __restrict__ w1,
                                             const float* __restrict__ b1,
                                             const float* __restrict__ w2,
                                             const float* __restrict__ b2,
                                             int relu_out) {
    __shared__ float zT[64 * ZS];   // [k][r]
    __shared__ float wsm[64 * 64];  // [k][j], holds w1 then w2
    int tid = threadIdx.x;
    int base = blockIdx.x * 64;
    int tr = tid & 15;   // row group: rows 4tr..4tr+3
    int tc = tid >> 4;   // col group: cols 4tc..4tc+3

    // ---- stage z = hin + agg, transposed into zT ----
    {
        int r = tid >> 2;  // 0..63
        int row = base + r;
        bool ok = row < NN;
#pragma unroll
        for (int i = 0; i < 4; ++i) {
            int cc = (tid & 3) + 4 * i;  // float4 col index 0..15
            float4 a = make_float4(0.f, 0.f, 0.f, 0.f);
            float4 g = make_float4(0.f, 0.f, 0.f, 0.f);
            if (ok) {
                a = reinterpret_cast<const float4*>(hin)[(size_t)row * 16 + cc];
                g = reinterpret_cast<const float4*>(agg)[(size_t)row * 16 + cc];
            }
            zT[(cc * 4 + 0) * ZS + r] = a.x + g.x;
            zT[(cc * 4 + 1) * ZS + r] = a.y + g.y;
            zT[(cc * 4 + 2) * ZS + r] = a.z + g.z;
            zT[(cc * 4 + 3) * ZS + r] = a.w + g.w;
        }
    }
    // ---- stage w1 ----
    {
        const float4* w4 = reinterpret_cast<const float4*>(w1);
        float4* s4 = reinterpret_cast<float4*>(wsm);
        for (int i = tid; i < 1024; i += 256) s4[i] = w4[i];
    }
    __syncthreads();

    // ---- layer 1: acc = zT^T @ w1 + b1 ----
    float4 bv = reinterpret_cast<const float4*>(b1)[tc];
    float acc[4][4];
#pragma unroll
    for (int rr = 0; rr < 4; ++rr) {
        acc[rr][0] = bv.x; acc[rr][1] = bv.y; acc[rr][2] = bv.z; acc[rr][3] = bv.w;
    }
#pragma unroll 8
    for (int k = 0; k < 64; ++k) {
        float4 zv = *reinterpret_cast<const float4*>(&zT[k * ZS + 4 * tr]);
        float4 wv = *reinterpret_cast<const float4*>(&wsm[k * 64 + 4 * tc]);
        const float zr[4] = {zv.x, zv.y, zv.z, zv.w};
        const float wc[4] = {wv.x, wv.y, wv.z, wv.w};
#pragma unroll
        for (int rr = 0; rr < 4; ++rr)
#pragma unroll
            for (int jj = 0; jj < 4; ++jj)
                acc[rr][jj] = fmaf(zr[rr], wc[jj], acc[rr][jj]);
    }
    __syncthreads();  // zT reads + wsm reads done

    // ---- write h1 = ReLU(acc) transposed back into zT; stage w2 ----
#pragma unroll
    for (int jj = 0; jj < 4; ++jj) {
        float4 hv;
        hv.x = fmaxf(acc[0][jj], 0.f);
        hv.y = fmaxf(acc[1][jj], 0.f);
        hv.z = fmaxf(acc[2][jj], 0.f);
        hv.w = fmaxf(acc[3][jj], 0.f);
        *reinterpret_cast<float4*>(&zT[(4 * tc + jj) * ZS + 4 * tr]) = hv;
    }
    {
        const float4* w4 = reinterpret_cast<const float4*>(w2);
        float4* s4 = reinterpret_cast<float4*>(wsm);
        for (int i = tid; i < 1024; i += 256) s4[i] = w4[i];
    }
    __syncthreads();

    // ---- layer 2: acc = h1T^T @ w2 + b2 ----
    bv = reinterpret_cast<const float4*>(b2)[tc];
#pragma unroll
    for (int rr = 0; rr < 4; ++rr) {
        acc[rr][0] = bv.x; acc[rr][1] = bv.y; acc[rr][2] = bv.z; acc[rr][3] = bv.w;
    }
#pragma unroll 8
    for (int k = 0; k < 64; ++k) {
        float4 zv = *reinterpret_cast<const float4*>(&zT[k * ZS + 4 * tr]);
        float4 wv = *reinterpret_cast<const float4*>(&wsm[k * 64 + 4 * tc]);
        const float zr[4] = {zv.x, zv.y, zv.z, zv.w};
        const float wc[4] = {wv.x, wv.y, wv.z, wv.w};
#pragma unroll
        for (int rr = 0; rr < 4; ++rr)
#pragma unroll
            for (int jj = 0; jj < 4; ++jj)
                acc[rr][jj] = fmaf(zr[rr], wc[jj], acc[rr][jj]);
    }

    // ---- store ----
#pragma unroll
    for (int rr = 0; rr < 4; ++rr) {
        int row = base + 4 * tr + rr;
        if (row < NN) {
            float4 o;
            o.x = acc[rr][0]; o.y = acc[rr][1]; o.z = acc[rr][2]; o.w = acc[rr][3];
            if (relu_out) {
                o.x = fmaxf(o.x, 0.f);
                o.y = fmaxf(o.y, 0.f);
                o.z = fmaxf(o.z, 0.f);
                o.w = fmaxf(o.w, 0.f);
            }
            reinterpret_cast<float4*>(hout)[(size_t)row * 16 + tc] = o;
        }
    }
}

// ---------------------------------------------------------------------------
// Pool + FC: one block per graph; batch sorted -> binary-search node range.
// ---------------------------------------------------------------------------
__device__ __forceinline__ int lower_bound_i(const int* __restrict__ a, int n, int v) {
    int lo = 0, hi = n;
    while (lo < hi) {
        int mid = (lo + hi) >> 1;
        if (a[mid] < v) lo = mid + 1; else hi = mid;
    }
    return lo;
}

__global__ __launch_bounds__(256) void pool_k(const float* __restrict__ h,
                                              const int* __restrict__ batch,
                                              const float* __restrict__ fcw,
                                              const float* __restrict__ fcb,
                                              float* __restrict__ out) {
    int g = blockIdx.x;
    int lane = threadIdx.x & 63;
    int wv = threadIdx.x >> 6;
    int lo = lower_bound_i(batch, NN, g);
    int hi = lower_bound_i(batch, NN, g + 1);
    float w = fcw[lane];
    float sum = 0.0f;
    for (int node = lo + wv; node < hi; node += 4)
        sum += h[(size_t)node * 64 + lane] * w;
#pragma unroll
    for (int off = 32; off > 0; off >>= 1) sum += __shfl_down(sum, off, 64);
    __shared__ float ws[4];
    if (lane == 0) ws[wv] = sum;
    __syncthreads();
    if (threadIdx.x == 0) out[g] = ws[0] + ws[1] + ws[2] + ws[3] + fcb[0];
}

extern "C" void kernel_launch(void* const* d_in, const int* in_sizes, int n_in,
                              void* d_out, int out_size, void* d_ws, size_t ws_size,
                              hipStream_t stream) {
    const float* x = (const float*)d_in[0];
    const int* ei = (const int*)d_in[1];     // [2, E] flat: src = ei[e], dst = ei[E+e]
    const int* batch = (const int*)d_in[2];  // [N], sorted
    const float* w[3][4];
    for (int l = 0; l < 3; ++l)
        for (int i = 0; i < 4; ++i) w[l][i] = (const float*)d_in[3 + l * 4 + i];
    const float* fcw = (const float*)d_in[15];
    const float* fcb = (const float*)d_in[16];
    float* out = (float*)d_out;

    // workspace layout
    float* agg = (float*)d_ws;                           // N*D floats (25.6 MB)
    float* hbuf = agg + (size_t)NN * DD;                 // N*D floats (25.6 MB)
    int* rowptr = (int*)(hbuf + (size_t)NN * DD);        // N+1 ints
    int* csr_src = rowptr + NN + 1;                      // E ints (6.4 MB)
    int* gbkt = csr_src + NE;                            // NBKT ints
    int* bbase = gbkt + NBKT;                            // NBKT ints
    int* bcur = bbase + NBKT;                            // NBKT ints
    // pairs alias agg: consumed by bfill_k before the first gather writes agg
    int2* pairs = (int2*)agg;                            // E int2 (12.8 MB)

    dim3 gblk(256), ggrid((NN + 3) / 4);
    dim3 mblk(256), mgrid((NN + 63) / 64);

    // Build CSR (dst-bucketed counting sort); amortized over 3 layers.
    hipMemsetAsync(gbkt, 0, NBKT * sizeof(int), stream);
    bhist_k<<<NEB, 256, 0, stream>>>(ei, gbkt);
    bscan_k<<<1, 512, 0, stream>>>(gbkt, bbase, bcur);
    pscat_k<<<NEB, 256, 0, stream>>>(ei, bcur, pairs);
    bfill_k<<<NBKT, 256, 0, stream>>>(pairs, bbase, gbkt, rowptr, csr_src);

    const float* hin = x;
    for (int l = 0; l < 3; ++l) {
        gather_k<<<ggrid, gblk, 0, stream>>>(hin, rowptr, csr_src, agg);
        mlp_k<<<mgrid, mblk, 0, stream>>>(hin, agg, hbuf, w[l][0], w[l][1], w[l][2],
                                          w[l][3], l < 2 ? 1 : 0);
        hin = hbuf;
    }
    pool_k<<<NG, 256, 0, stream>>>(hbuf, batch, fcw, fcb, out);
}